// Round 11
// baseline (120.999 us; speedup 1.0000x reference)
//
#include <hip/hip_runtime.h>
#include <hip/hip_cooperative_groups.h>
#include <cstddef>
#include <math.h>

namespace cg = cooperative_groups;

#define BD 8
#define TD 256
#define SD 256
#define HD 512
#define K2F 2.885390081777927f    // 2*log2(e): arg of exp2 for e^(2x)

#define EXP2(x) __builtin_amdgcn_exp2f(x)
#define RCP(x)  __builtin_amdgcn_rcpf(x)

typedef __attribute__((ext_vector_type(8))) _Float16 half8;
typedef __attribute__((ext_vector_type(4))) float float4v;

// exp2 with arg clamped so E in [2^-80, 2^80]: products overflow to inf -> rcp -> 0,
// underflow to 0 -> r = 1; no inf*0 NaN path possible.
__device__ __forceinline__ float exp2_sat(float x) {
    return EXP2(fminf(fmaxf(x, -80.0f), 80.0f));
}

__device__ __forceinline__ half8 to_h8(float4 lo, float4 hi) {
    half8 h;
    h[0]=(_Float16)lo.x; h[1]=(_Float16)lo.y; h[2]=(_Float16)lo.z; h[3]=(_Float16)lo.w;
    h[4]=(_Float16)hi.x; h[5]=(_Float16)hi.y; h[6]=(_Float16)hi.z; h[7]=(_Float16)hi.w;
    return h;
}

// ============ fused cooperative kernel: barrier-free proj -> grid.sync -> attn ============
__global__ __launch_bounds__(512) void fused_kernel(
    const float* __restrict__ enc,   // (B,S,H)
    const float* __restrict__ qry,   // (B,T,H)
    const float* __restrict__ Wh,    // (H,H)
    const float* __restrict__ Ws,    // (H,H)
    const float* __restrict__ v,     // (H)
    const int*   __restrict__ lens,  // (B)
    float* __restrict__ encT,        // ws: (B,H,S) E_e
    float* __restrict__ qryf,        // ws: (B,T,H) E_q
    float* __restrict__ out)         // (B,T,H)
{
    __shared__ float smem[7168];     // 28 KB (phase B only)

    const int bid = blockIdx.x;      // 0..511
    const int tid = threadIdx.x;     // 0..511
    const int l   = tid & 63;
    const int w   = tid >> 6;        // wave 0..7
    const int rf  = l & 15;
    const int q   = l >> 4;

    // ===== PHASE A: proj, NO LDS / NO BARRIERS — MFMA fragments loaded direct =====
    // A-frag lane(rf,q) = A[row = strip + rf][k = k0 + q*8 .. +7]: contiguous 32 B.
    {
        const int my = bid >> 3;
        const bool isq = my >= 32;
        const int m0 = my * 64;                    // stacked row 0..4095
        const int n0 = (bid & 7) * 64;
        const int mi = (w & 3) * 16;               // wave row-strip
        const int ni = (w >> 2) * 32;              // wave col-strip (2 MFMA tiles)

        const float* Arow = (isq ? qry + (size_t)(m0 - 2048 + mi + rf) * HD
                                 : enc + (size_t)(m0 + mi + rf) * HD) + q * 8;
        const float* Brow0 = (isq ? Ws : Wh) + (size_t)(n0 + ni + rf) * HD + q * 8;
        const float* Brow1 = Brow0 + (size_t)16 * HD;

        float4v acc[2] = {{0,0,0,0},{0,0,0,0}};

        #pragma unroll 2
        for (int ks = 0; ks < 16; ++ks) {
            const int k0 = ks * 32;
            float4 al  = *(const float4*)(Arow + k0);
            float4 ah  = *(const float4*)(Arow + k0 + 4);
            float4 b0l = *(const float4*)(Brow0 + k0);
            float4 b0h = *(const float4*)(Brow0 + k0 + 4);
            float4 b1l = *(const float4*)(Brow1 + k0);
            float4 b1h = *(const float4*)(Brow1 + k0 + 4);
            half8 ha  = to_h8(al, ah);
            half8 hb0 = to_h8(b0l, b0h);
            half8 hb1 = to_h8(b1l, b1h);
            acc[0] = __builtin_amdgcn_mfma_f32_16x16x32_f16(ha, hb0, acc[0], 0, 0, 0);
            acc[1] = __builtin_amdgcn_mfma_f32_16x16x32_f16(ha, hb1, acc[1], 0, 0, 0);
        }

        // Epilogue (verified map: m-local = mi + q*4 + r, n-local = ni + j*16 + rf).
        if (!isq) {
            const int b  = m0 >> 8;
            const int sb = (m0 & 255) + mi + q * 4;
            float* base = encT + (size_t)b * HD * SD;
            #pragma unroll
            for (int j = 0; j < 2; ++j) {
                float4 o = make_float4(exp2_sat(acc[j][0]*K2F), exp2_sat(acc[j][1]*K2F),
                                       exp2_sat(acc[j][2]*K2F), exp2_sat(acc[j][3]*K2F));
                *(float4*)(base + (size_t)(n0 + ni + j * 16 + rf) * SD + sb) = o;
            }
        } else {
            const int mrow = (m0 - 2048) + mi + q * 4;
            #pragma unroll
            for (int j = 0; j < 2; ++j)
                #pragma unroll
                for (int r = 0; r < 4; ++r)
                    qryf[(size_t)(mrow + r) * HD + n0 + ni + j * 16 + rf] =
                        exp2_sat(acc[j][r] * K2F);
        }
    }

    cg::this_grid().sync();   // device-scope: encT/qryf visible to all blocks

    // ================= PHASE B: attn (R10 structure, 28 KB LDS) =================
    {
        float* qls = smem;            // [j][t] 2048 floats
        float* pls = smem + 2048;     // [slice(4)][t(4)][s(256)] 4096 floats; aliased avred
        float* wls = smem + 6144;     // [t][s] 1024 floats

        const int b  = bid >> 6;
        const int t0 = (bid & 63) * 4;

        {   // stage E_q transposed: qls[j*4+t]
            const float* qf = qryf + ((size_t)b * TD + t0) * HD;
            float4 qv;
            qv.x = qf[0 * HD + tid]; qv.y = qf[1 * HD + tid];
            qv.z = qf[2 * HD + tid]; qv.w = qf[3 * HD + tid];
            *(float4*)&qls[tid * 4] = qv;
        }
        __syncthreads();

        // ---- scores: wave w covers j-slice w; lane owns s = 4l..4l+3 ----
        float a[4][4];
        #pragma unroll
        for (int t = 0; t < 4; ++t)
            #pragma unroll
            for (int c = 0; c < 4; ++c) a[t][c] = 0.0f;
        {
            const float* ep = encT + (size_t)b * HD * SD + (size_t)(w * 64) * SD + l * 4;
            const int jbase = w * 64;
            #pragma unroll 4
            for (int jj = 0; jj < 64; ++jj) {
                float4 e = *(const float4*)(ep + (size_t)jj * SD);  // E_e, coalesced
                float4 q4 = *(const float4*)&qls[(jbase + jj) * 4]; // E_q, broadcast
                float vj = v[jbase + jj];                           // uniform -> s_load
                float ev[4] = {e.x, e.y, e.z, e.w};
                float qv[4] = {q4.x, q4.y, q4.z, q4.w};
                #pragma unroll
                for (int t = 0; t < 4; ++t)
                    #pragma unroll
                    for (int c = 0; c < 4; ++c) {
                        float p = fmaf(ev[c], qv[t], 1.0f);
                        a[t][c] = fmaf(vj, RCP(p), a[t][c]);
                    }
            }
        }
        // two-stage partial accumulate (keeps pls at 16 KB)
        if (w < 4) {
            #pragma unroll
            for (int t = 0; t < 4; ++t)
                *(float4*)&pls[(w * 4 + t) * 256 + l * 4] =
                    make_float4(a[t][0], a[t][1], a[t][2], a[t][3]);
        }
        __syncthreads();
        if (w >= 4) {
            #pragma unroll
            for (int t = 0; t < 4; ++t) {
                float4 c4 = *(const float4*)&pls[((w - 4) * 4 + t) * 256 + l * 4];
                c4.x += a[t][0]; c4.y += a[t][1]; c4.z += a[t][2]; c4.w += a[t][3];
                *(float4*)&pls[((w - 4) * 4 + t) * 256 + l * 4] = c4;
            }
        }
        __syncthreads();

        // ---- combine 4 slices + masked softmax: wave t<4 handles t; lane owns 4 s ----
        if (w < 4) {
            const int t = w;
            float p[4] = {0, 0, 0, 0};
            #pragma unroll
            for (int g = 0; g < 4; ++g) {
                float4 pp = *(const float4*)&pls[(g * 4 + t) * 256 + l * 4];
                p[0] += pp.x; p[1] += pp.y; p[2] += pp.z; p[3] += pp.w;
            }
            const int len = lens[b];
            const int s0 = l * 4;
            float sc[4];
            #pragma unroll
            for (int c = 0; c < 4; ++c)
                sc[c] = (s0 + c < len) ? -2.0f * p[c] : -INFINITY;
            float mx = fmaxf(fmaxf(sc[0], sc[1]), fmaxf(sc[2], sc[3]));
            #pragma unroll
            for (int off = 32; off; off >>= 1) mx = fmaxf(mx, __shfl_xor(mx, off));
            float ex[4]; float sum = 0.0f;
            #pragma unroll
            for (int c = 0; c < 4; ++c) { ex[c] = __expf(sc[c] - mx); sum += ex[c]; }
            #pragma unroll
            for (int off = 32; off; off >>= 1) sum += __shfl_xor(sum, off);
            const float inv = RCP(sum);
            *(float4*)&wls[t * SD + s0] = make_float4(ex[0]*inv, ex[1]*inv, ex[2]*inv, ex[3]*inv);
        }
        __syncthreads();

        // ---- AV: thread owns (h-float4, s-slice sg); accumulates all 4 t ----
        const int sg = tid >> 7;          // 0..3 (wave-uniform)
        const int h4 = (tid & 127) * 4;
        float* avred = pls;               // [slice(2)][t(4)][h(512)]
        float4 o[4] = {{0,0,0,0},{0,0,0,0},{0,0,0,0},{0,0,0,0}};
        {
            const float* eb = enc + (size_t)b * SD * HD + h4;
            #pragma unroll 2
            for (int ss = 0; ss < 64; ++ss) {
                const int s = sg * 64 + ss;
                float4 evv = *(const float4*)(eb + (size_t)s * HD);
                float wt[4];
                #pragma unroll
                for (int t = 0; t < 4; ++t) wt[t] = wls[t * SD + s];
                #pragma unroll
                for (int t = 0; t < 4; ++t) {
                    o[t].x = fmaf(wt[t], evv.x, o[t].x);
                    o[t].y = fmaf(wt[t], evv.y, o[t].y);
                    o[t].z = fmaf(wt[t], evv.z, o[t].z);
                    o[t].w = fmaf(wt[t], evv.w, o[t].w);
                }
            }
        }
        if (sg < 2) {
            #pragma unroll
            for (int t = 0; t < 4; ++t)
                *(float4*)&avred[(size_t)(sg * 4 + t) * 512 + h4] = o[t];
        }
        __syncthreads();
        if (sg >= 2) {
            #pragma unroll
            for (int t = 0; t < 4; ++t) {
                float4 c4 = *(const float4*)&avred[(size_t)((sg - 2) * 4 + t) * 512 + h4];
                c4.x += o[t].x; c4.y += o[t].y; c4.z += o[t].z; c4.w += o[t].w;
                *(float4*)&avred[(size_t)((sg - 2) * 4 + t) * 512 + h4] = c4;
            }
        }
        __syncthreads();

        // final reduce + store: thread owns (t = tid>>7, h-float4)
        {
            const int t  = tid >> 7;
            const int hh = (tid & 127) * 4;
            float4 x0 = *(const float4*)&avred[(size_t)(0 * 4 + t) * 512 + hh];
            float4 x1 = *(const float4*)&avred[(size_t)(1 * 4 + t) * 512 + hh];
            float4 r = make_float4(x0.x + x1.x, x0.y + x1.y, x0.z + x1.z, x0.w + x1.w);
            *(float4*)(out + ((size_t)b * TD + t0 + t) * HD + hh) = r;
        }
    }
}

// ================= fallback pair (proven R8 proj + R7 attn) =================
#define LSTR 40
typedef __attribute__((ext_vector_type(8))) _Float16 half8fb;

__global__ __launch_bounds__(256) void proj_fb(
    const float* __restrict__ enc, const float* __restrict__ qry,
    const float* __restrict__ Wh,  const float* __restrict__ Ws,
    float* __restrict__ encT, float* __restrict__ qryf)
{
    __shared__ _Float16 LA[64 * LSTR], LB[64 * LSTR];

    const int tid = threadIdx.x;
    const int l = tid & 63, w = tid >> 6;
    const int rf = l & 15, q = l >> 4;
    const int my = blockIdx.y;
    const bool isq = my >= 32;
    const int m0 = my * 64;
    const int n0 = blockIdx.x * 64;

    const int srow = tid >> 2;
    const int scol = (tid & 3) * 8;
    const float* Abase = isq
        ? qry + (size_t)(m0 - 2048 + srow) * HD + scol
        : enc + (size_t)(m0 + srow) * HD + scol;
    const float* Bbase = (isq ? Ws : Wh) + (size_t)(n0 + srow) * HD + scol;

    const int mi = (w & 1) * 32, ni = (w >> 1) * 32;
    float4v acc[2][2] = {{{0,0,0,0},{0,0,0,0}},{{0,0,0,0},{0,0,0,0}}};

    float4 a0 = *(const float4*)(Abase);
    float4 a1 = *(const float4*)(Abase + 4);
    float4 b0 = *(const float4*)(Bbase);
    float4 b1 = *(const float4*)(Bbase + 4);

    for (int ks = 0; ks < 16; ++ks) {
        if (ks) __syncthreads();
        {
            half8fb ha = to_h8(a0, a1), hb = to_h8(b0, b1);
            *(half8fb*)&LA[srow * LSTR + scol] = ha;
            *(half8fb*)&LB[srow * LSTR + scol] = hb;
        }
        __syncthreads();
        if (ks + 1 < 16) {
            const int ko = (ks + 1) * 32;
            a0 = *(const float4*)(Abase + ko);
            a1 = *(const float4*)(Abase + ko + 4);
            b0 = *(const float4*)(Bbase + ko);
            b1 = *(const float4*)(Bbase + ko + 4);
        }
        half8fb ah[2], bh[2];
        #pragma unroll
        for (int i = 0; i < 2; ++i) {
            ah[i] = *(const half8fb*)&LA[(mi + i * 16 + rf) * LSTR + q * 8];
            bh[i] = *(const half8fb*)&LB[(ni + i * 16 + rf) * LSTR + q * 8];
        }
        #pragma unroll
        for (int i = 0; i < 2; ++i)
            #pragma unroll
            for (int j = 0; j < 2; ++j)
                acc[i][j] = __builtin_amdgcn_mfma_f32_16x16x32_f16(ah[i], bh[j], acc[i][j], 0, 0, 0);
    }

    if (!isq) {
        const int b  = m0 >> 8;
        const int sb = (m0 & 255) + mi + q * 4;
        float* base = encT + (size_t)b * HD * SD;
        #pragma unroll
        for (int i = 0; i < 2; ++i)
            #pragma unroll
            for (int j = 0; j < 2; ++j) {
                float4 o = make_float4(exp2_sat(acc[i][j][0]*K2F), exp2_sat(acc[i][j][1]*K2F),
                                       exp2_sat(acc[i][j][2]*K2F), exp2_sat(acc[i][j][3]*K2F));
                *(float4*)(base + (size_t)(n0 + ni + j * 16 + rf) * SD + sb + i * 16) = o;
            }
    } else {
        const int mrow = (m0 - 2048) + mi + q * 4;
        #pragma unroll
        for (int i = 0; i < 2; ++i)
            #pragma unroll
            for (int j = 0; j < 2; ++j)
                #pragma unroll
                for (int r = 0; r < 4; ++r)
                    qryf[(size_t)(mrow + i * 16 + r) * HD + n0 + ni + j * 16 + rf] =
                        exp2_sat(acc[i][j][r] * K2F);
    }
}

__global__ __launch_bounds__(512) void attn_fb(
    const float* __restrict__ enc, const float* __restrict__ encT,
    const float* __restrict__ qryf, const float* __restrict__ v,
    const int* __restrict__ lens, float* __restrict__ out)
{
    __shared__ float qls[HD * 4];
    __shared__ float pls[8 * 4 * 256];
    __shared__ float wls[4 * SD];

    const int blk = blockIdx.x;
    const int b   = blk >> 6;
    const int t0  = (blk & 63) * 4;
    const int tid = threadIdx.x;
    const int w   = tid >> 6;
    const int l   = tid & 63;

    {
        const float* qf = qryf + ((size_t)b * TD + t0) * HD;
        float4 qv;
        qv.x = qf[0 * HD + tid]; qv.y = qf[1 * HD + tid];
        qv.z = qf[2 * HD + tid]; qv.w = qf[3 * HD + tid];
        *(float4*)&qls[tid * 4] = qv;
    }
    __syncthreads();

    float a[4][4];
    #pragma unroll
    for (int t = 0; t < 4; ++t)
        #pragma unroll
        for (int c = 0; c < 4; ++c) a[t][c] = 0.0f;
    {
        const float* ep = encT + (size_t)b * HD * SD + (size_t)(w * 64) * SD + l * 4;
        const int jbase = w * 64;
        #pragma unroll 4
        for (int jj = 0; jj < 64; ++jj) {
            float4 e = *(const float4*)(ep + (size_t)jj * SD);
            float4 q4 = *(const float4*)&qls[(jbase + jj) * 4];
            float vj = v[jbase + jj];
            float ev[4] = {e.x, e.y, e.z, e.w};
            float qv[4] = {q4.x, q4.y, q4.z, q4.w};
            #pragma unroll
            for (int t = 0; t < 4; ++t)
                #pragma unroll
                for (int c = 0; c < 4; ++c) {
                    float p = fmaf(ev[c], qv[t], 1.0f);
                    a[t][c] = fmaf(vj, RCP(p), a[t][c]);
                }
        }
    }
    #pragma unroll
    for (int t = 0; t < 4; ++t)
        *(float4*)&pls[(w * 4 + t) * 256 + l * 4] = make_float4(a[t][0], a[t][1], a[t][2], a[t][3]);
    __syncthreads();

    if (w < 4) {
        const int t = w;
        float p[4] = {0, 0, 0, 0};
        #pragma unroll
        for (int g = 0; g < 8; ++g) {
            float4 pp = *(const float4*)&pls[(g * 4 + t) * 256 + l * 4];
            p[0] += pp.x; p[1] += pp.y; p[2] += pp.z; p[3] += pp.w;
        }
        const int len = lens[b];
        const int s0 = l * 4;
        float sc[4];
        #pragma unroll
        for (int c = 0; c < 4; ++c)
            sc[c] = (s0 + c < len) ? -2.0f * p[c] : -INFINITY;
        float mx = fmaxf(fmaxf(sc[0], sc[1]), fmaxf(sc[2], sc[3]));
        #pragma unroll
        for (int off = 32; off; off >>= 1) mx = fmaxf(mx, __shfl_xor(mx, off));
        float ex[4]; float sum = 0.0f;
        #pragma unroll
        for (int c = 0; c < 4; ++c) { ex[c] = __expf(sc[c] - mx); sum += ex[c]; }
        #pragma unroll
        for (int off = 32; off; off >>= 1) sum += __shfl_xor(sum, off);
        const float inv = RCP(sum);
        *(float4*)&wls[t * SD + s0] = make_float4(ex[0]*inv, ex[1]*inv, ex[2]*inv, ex[3]*inv);
    }
    __syncthreads();

    const int g  = tid >> 7;
    const int h4 = (tid & 127) * 4;
    float* avred = pls;
    {
        const float* eb = enc + (size_t)b * SD * HD + h4;
        float4 o[4] = {{0,0,0,0},{0,0,0,0},{0,0,0,0},{0,0,0,0}};
        #pragma unroll 2
        for (int ss = 0; ss < 64; ++ss) {
            const int s = g * 64 + ss;
            float4 evv = *(const float4*)(eb + (size_t)s * HD);
            float wt[4];
            #pragma unroll
            for (int t = 0; t < 4; ++t) wt[t] = wls[t * SD + s];
            #pragma unroll
            for (int t = 0; t < 4; ++t) {
                o[t].x = fmaf(wt[t], evv.x, o[t].x);
                o[t].y = fmaf(wt[t], evv.y, o[t].y);
                o[t].z = fmaf(wt[t], evv.z, o[t].z);
                o[t].w = fmaf(wt[t], evv.w, o[t].w);
            }
        }
        #pragma unroll
        for (int t = 0; t < 4; ++t)
            *(float4*)&avred[(size_t)(g * 4 + t) * 512 + h4] = o[t];
    }
    __syncthreads();
    {
        const int t  = tid >> 7;
        const int hh = (tid & 127) * 4;
        float4 r = {0, 0, 0, 0};
        #pragma unroll
        for (int gg = 0; gg < 4; ++gg) {
            float4 x = *(const float4*)&avred[(size_t)(gg * 4 + t) * 512 + hh];
            r.x += x.x; r.y += x.y; r.z += x.z; r.w += x.w;
        }
        *(float4*)(out + ((size_t)b * TD + t0 + t) * HD + hh) = r;
    }
}

extern "C" void kernel_launch(void* const* d_in, const int* in_sizes, int n_in,
                              void* d_out, int out_size, void* d_ws, size_t ws_size,
                              hipStream_t stream) {
    const float* query = (const float*)d_in[0];
    const float* enc   = (const float*)d_in[1];
    const int*   lens  = (const int*)d_in[2];
    const float* W_h   = (const float*)d_in[3];
    const float* W_s   = (const float*)d_in[4];
    const float* v     = (const float*)d_in[5];
    float* out = (float*)d_out;

    char* ws = (char*)d_ws;
    float* encT = (float*)(ws);                       // 4 MB (B,H,S)  E_e
    float* qryf = (float*)(ws + ((size_t)4 << 20));   // 4 MB (B,T,H)  E_q

    // Host-side occupancy pre-screen (pure query — graph-safe, deterministic).
    int nb = 0;
    hipError_t oerr = hipOccupancyMaxActiveBlocksPerMultiprocessor(
        &nb, (const void*)fused_kernel, 512, 0);
    bool coop_ok = (oerr == hipSuccess) && (nb * 256 >= 512);

    if (coop_ok) {
        void* args[] = {
            (void*)&enc, (void*)&query, (void*)&W_h, (void*)&W_s,
            (void*)&v, (void*)&lens, (void*)&encT, (void*)&qryf, (void*)&out
        };
        hipError_t lerr = hipLaunchCooperativeKernel((const void*)fused_kernel,
                                                     dim3(512), dim3(512), args, 0, stream);
        if (lerr == hipSuccess) return;
    }

    // Fallback: proven two-kernel path.
    dim3 pgrid(HD / 64, 64);
    proj_fb<<<pgrid, 256, 0, stream>>>(enc, query, W_h, W_s, encT, qryf);
    attn_fb<<<BD * (TD / 4), 512, 0, stream>>>(enc, encT, qryf, v, lens, out);
}